// Round 16
// baseline (15.418 us; speedup 1.0000x reference)
//
#include <hip/hip_runtime.h>
#include <hip/hip_bf16.h>

// S=128, Q=8192, H=230
//   logits[s,q] = a[s] + c[q] + b - 2*sum_k (w*x)[s,k]*y[q,k]
// r15 champion (14.7us) with ONE delta: s-split 2 -> grid 512, block 256
// (4 waves), 2 blocks/CU for cross-block latency overlap. Block covers
// 64 s x 32 q; blocks sharing a y-tile are 256 apart (same XCD slot).
// Per-wave structure unchanged: A-frags bf16(w*x) in regs pre-barrier,
// a[s] via shfl_xor -> asl, swizzled bf16 y-tile, 2-acc MFMA, fused epilogue.
// Loss: per-block partial + tiny deterministic reduce kernel.

#define S_DIM 128
#define Q_DIM 8192
#define H_DIM 230
#define K2    256              // bf16 K padded to multiple of 32
#define SQ    (S_DIM * Q_DIM)
#define QB    32               // q-tile per block
#define NQT   (Q_DIM / QB)     // 256 q-tiles
#define NBLK  (NQT * 2)        // 512 main blocks (2 s-splits)

using short8 = __attribute__((ext_vector_type(8))) short;   // 8 bf16 (4 VGPRs)
using f32x4  = __attribute__((ext_vector_type(4))) float;

__device__ __forceinline__ float bf16_to_f32(short bits) {
    unsigned u = ((unsigned)(unsigned short)bits) << 16;
    return __uint_as_float(u);
}
__device__ __forceinline__ unsigned short bf16bits(float f) {
    __hip_bfloat16 h = __float2bfloat16(f);
    return *reinterpret_cast<unsigned short*>(&h);
}
__device__ __forceinline__ unsigned packbf2(float lo, float hi) {
    return (unsigned)bf16bits(lo) | ((unsigned)bf16bits(hi) << 16);
}

// ---------------- Kernel 1: main (MFMA GEMM + sigmoid + BCE) ----------------
// grid=512, block=256 (4 waves). Block: 64 s x 32 q.
// qt = bid & 255 (q-tile), ss = bid >> 8 (s-half). Wave wid: s rows
// [64*ss + 16*wid, +16), q-halves [q0,q0+16) and [q0+16,q0+32).
__global__ __launch_bounds__(256, 2) void main_kernel(
    const float* __restrict__ x, const float* __restrict__ y,
    const int* __restrict__ label, const float* __restrict__ w,
    const float* __restrict__ bptr, float* __restrict__ out,
    float* __restrict__ lossws)
{
    __shared__ __align__(16) short ylb[QB * K2];   // 16 KB bf16, XOR-swizzled
    __shared__ float cpart[8][33];
    __shared__ float cq[QB];
    __shared__ float asl[64];
    __shared__ float lred[4];

    const int tid = threadIdx.x, bid = blockIdx.x;
    const int qt = bid & (NQT - 1), ss = bid >> 8;
    const int q0 = qt * QB;
    const int wid = tid >> 6, l = tid & 63;
    const int lm = l & 15, lh = l >> 4;
    const int s_loc_base = wid * 16;               // local s base (0..48)
    const int s_glob_base = ss * 64 + s_loc_base;  // global s base
    char* ylc = reinterpret_cast<char*>(ylb);

    // ---- stage y tile (32 rows x 230 f32) -> bf16 swizzled LDS ----
    // One contiguous span of 32*230 = 7360 f32 = 1840 float4, 16B-aligned.
    const float4* ysrc4 = reinterpret_cast<const float4*>(y + (size_t)q0 * H_DIM);
    #pragma unroll
    for (int it = 0; it < 8; ++it) {
        int i4 = tid + 256 * it;
        if (i4 < (QB * H_DIM) / 4) {
            float4 v = ysrc4[i4];
            int e0 = i4 * 4;
            int r0 = e0 / H_DIM;               // const divide -> magic mul
            int c0 = e0 - r0 * H_DIM;          // even
            int e2 = e0 + 2;
            int r2 = e2 / H_DIM;
            int c2 = e2 - r2 * H_DIM;          // even
            int byt0 = ((r0 << 9) + (c0 << 1)) ^ ((r0 & 7) << 4);
            int byt2 = ((r2 << 9) + (c2 << 1)) ^ ((r2 & 7) << 4);
            *reinterpret_cast<unsigned*>(ylc + byt0) = packbf2(v.x, v.y);
            *reinterpret_cast<unsigned*>(ylc + byt2) = packbf2(v.z, v.w);
        }
    }
    #pragma unroll
    for (int it = 0; it < 2; ++it) {   // zero-fill k=230..255: 32 rows x 13 pairs
        int idx = tid + 256 * it;
        if (idx < QB * (K2 - H_DIM) / 2) {
            int r = idx & 31, c = H_DIM + 2 * (idx >> 5);
            int byt = ((r << 9) + (c << 1)) ^ ((r & 7) << 4);
            *reinterpret_cast<unsigned*>(ylc + byt) = 0u;
        }
    }

    // ---- label prefetch: issue AFTER staging reads, consume in epilogue ----
    int labs[2][4];
    {
        const size_t ob = (size_t)(s_glob_base + lh * 4) * Q_DIM + q0 + lm;
        #pragma unroll
        for (int r = 0; r < 4; ++r) {
            labs[0][r] = label[ob + (size_t)r * Q_DIM];
            labs[1][r] = label[ob + (size_t)r * Q_DIM + 16];
        }
    }

    // ---- A-frags + a[s] in registers (pre-barrier; overlaps y staging) ----
    short8 afr[8];
    {
        float ap = 0.f;
        const float* xrow = x + (size_t)(s_glob_base + lm) * H_DIM;
        #pragma unroll
        for (int ks = 0; ks < 8; ++ks) {
            const int kof = ks * 32 + lh * 8;
            short8 a;
            #pragma unroll
            for (int j = 0; j < 4; ++j) {
                int k = kof + 2 * j;
                float2 x2 = {0.f, 0.f}, w2 = {0.f, 0.f};
                if (k < H_DIM) {
                    x2 = *reinterpret_cast<const float2*>(xrow + k);
                    w2 = *reinterpret_cast<const float2*>(w + k);
                }
                float p0 = w2.x * x2.x, p1 = w2.y * x2.y;
                a[2 * j]     = (short)bf16bits(p0);
                a[2 * j + 1] = (short)bf16bits(p1);
                ap = fmaf(p1, x2.y, fmaf(p0, x2.x, ap));   // w*x^2 (f32)
            }
            afr[ks] = a;
        }
        ap += __shfl_xor(ap, 16, 64);
        ap += __shfl_xor(ap, 32, 64);
        if (lh == 0) asl[s_loc_base + lm] = ap;
    }

    __syncthreads();

    // ---- c[q] partials: r=tid&31 (q-row), ch=tid>>5 (32 k each) ----
    {
        const int r = tid & 31, ch = tid >> 5;     // ch in 0..7
        const int k0 = ch * 32;
        float p = 0.f;
        #pragma unroll
        for (int half = 0; half < 4; ++half) {
            int kk = k0 + half * 8;
            int byt = ((r << 9) + (kk << 1)) ^ ((r & 7) << 4);
            short8 v8 = *reinterpret_cast<const short8*>(ylc + byt);
            #pragma unroll
            for (int j = 0; j < 8; ++j) {
                float v = bf16_to_f32(v8[j]);
                float wk = (kk + j < H_DIM) ? w[kk + j] : 0.f;
                p = fmaf(wk * v, v, p);
            }
        }
        cpart[ch][r] = p;
    }
    __syncthreads();
    if (tid < QB) {
        float c = 0.f;
        #pragma unroll
        for (int ch = 0; ch < 8; ++ch) c += cpart[ch][tid];
        cq[tid] = c + bptr[0];                     // fold bias in
    }
    __syncthreads();

    // ---- MFMA k-loop: wave computes 16 s x 32 q (2 accs, A from registers) ----
    f32x4 acc0 = {0.f, 0.f, 0.f, 0.f};
    f32x4 acc1 = {0.f, 0.f, 0.f, 0.f};
    #pragma unroll
    for (int ks = 0; ks < K2 / 32; ++ks) {
        const int kof = ks * 32 + lh * 8;
        int byt0 = ((lm << 9) + (kof << 1)) ^ ((lm & 7) << 4);
        int byt1 = (((lm + 16) << 9) + (kof << 1)) ^ ((lm & 7) << 4);
        short8 bf0 = *reinterpret_cast<const short8*>(ylc + byt0);
        short8 bf1 = *reinterpret_cast<const short8*>(ylc + byt1);
        acc0 = __builtin_amdgcn_mfma_f32_16x16x32_bf16(afr[ks], bf0, acc0, 0, 0, 0);
        acc1 = __builtin_amdgcn_mfma_f32_16x16x32_bf16(afr[ks], bf1, acc1, 0, 0, 0);
    }

    // ---- epilogue: z = a[s]+c[q]+b-2*dot ; sigmoid -> out ; BCE partial ----
    // bce = z*(1-lab) + log(1+exp(-z)), sharing exp(-z) with the sigmoid.
    float lsum = 0.f;
    const float cq0 = cq[lm], cq1 = cq[lm + 16];
    #pragma unroll
    for (int r = 0; r < 4; ++r) {
        int s_loc = s_loc_base + lh * 4 + r;       // D row=(l>>4)*4+r, col=l&15
        int s = ss * 64 + s_loc;
        size_t o = (size_t)s * Q_DIM + q0 + lm;
        {
            float z = asl[s_loc] + cq0 - 2.0f * acc0[r];
            float ez = __expf(-z);
            out[o] = 1.0f / (1.0f + ez);
            float lab = (float)labs[0][r];
            lsum += z * (1.0f - lab) + __logf(1.0f + ez);
        }
        {
            float z = asl[s_loc] + cq1 - 2.0f * acc1[r];
            float ez = __expf(-z);
            out[o + 16] = 1.0f / (1.0f + ez);
            float lab = (float)labs[1][r];
            lsum += z * (1.0f - lab) + __logf(1.0f + ez);
        }
    }
    #pragma unroll
    for (int off = 32; off >= 1; off >>= 1) lsum += __shfl_down(lsum, off, 64);
    if (l == 0) lred[wid] = lsum;
    __syncthreads();
    if (tid == 0)
        lossws[bid] = lred[0] + lred[1] + lred[2] + lred[3];
}

// ---------------- Kernel 2: deterministic loss reduce ----------------
__global__ __launch_bounds__(256) void loss_reduce_kernel(
    const float* __restrict__ lossws, float* __restrict__ out)
{
    __shared__ float lred[4];
    const int tid = threadIdx.x;
    float p = lossws[tid] + lossws[tid + 256];     // NBLK=512 partials
    #pragma unroll
    for (int off = 32; off >= 1; off >>= 1) p += __shfl_down(p, off, 64);
    if ((tid & 63) == 0) lred[tid >> 6] = p;
    __syncthreads();
    if (tid == 0)
        out[SQ] = (lred[0] + lred[1] + lred[2] + lred[3]) * (1.0f / (float)SQ);
}

extern "C" void kernel_launch(void* const* d_in, const int* in_sizes, int n_in,
                              void* d_out, int out_size, void* d_ws, size_t ws_size,
                              hipStream_t stream) {
    const float* x = (const float*)d_in[0];     // [128,230]
    const float* y = (const float*)d_in[1];     // [8192,230]
    const int* label = (const int*)d_in[2];     // [128,8192]
    const float* w = (const float*)d_in[3];     // [230]
    const float* b = (const float*)d_in[4];     // [1]
    float* out = (float*)d_out;                 // [128*8192 + 1]

    float* lossws = (float*)d_ws;               // [512]

    main_kernel<<<NBLK, 256, 0, stream>>>(x, y, label, w, b, out, lossws);
    loss_reduce_kernel<<<1, 256, 0, stream>>>(lossws, out);
}

// Round 17
// 14.846 us; speedup vs baseline: 1.0385x; 1.0385x over previous
//
#include <hip/hip_runtime.h>
#include <hip/hip_bf16.h>

// S=128, Q=8192, H=230
//   logits[s,q] = a[s] + c[q] + b - 2*sum_k (w*x)[s,k]*y[q,k]
// r15 champion (14.7us) + LDS-transposed epilogue:
//   MFMA z results -> scb[128][36] f32 LDS -> barrier -> q-contiguous store
//   phase: labels as int4 (coalesced, prefetched), scores as float4, sigmoid
//   + BCE computed in store phase sharing one exp per element.
// Loss: per-block partial + tiny deterministic reduce kernel.

#define S_DIM 128
#define Q_DIM 8192
#define H_DIM 230
#define K2    256              // bf16 K padded to multiple of 32
#define SQ    (S_DIM * Q_DIM)
#define QB    32               // q-tile per block
#define NBLK  (Q_DIM / QB)     // 256 main blocks
#define SCB_W 36               // scb row stride (f32): 144B, 16B-aligned, bank-safe

using short8 = __attribute__((ext_vector_type(8))) short;   // 8 bf16 (4 VGPRs)
using f32x4  = __attribute__((ext_vector_type(4))) float;

__device__ __forceinline__ float bf16_to_f32(short bits) {
    unsigned u = ((unsigned)(unsigned short)bits) << 16;
    return __uint_as_float(u);
}
__device__ __forceinline__ unsigned short bf16bits(float f) {
    __hip_bfloat16 h = __float2bfloat16(f);
    return *reinterpret_cast<unsigned short*>(&h);
}
__device__ __forceinline__ unsigned packbf2(float lo, float hi) {
    return (unsigned)bf16bits(lo) | ((unsigned)bf16bits(hi) << 16);
}

// ---------------- Kernel 1: main (MFMA GEMM + sigmoid + BCE) ----------------
// grid=256, block=512 (8 waves). Block: all 128 s x 32 q.
// Wave wid: s in [16*wid, 16*wid+16), q-halves [q0,q0+16) and [q0+16,q0+32).
__global__ __launch_bounds__(512, 2) void main_kernel(
    const float* __restrict__ x, const float* __restrict__ y,
    const int* __restrict__ label, const float* __restrict__ w,
    const float* __restrict__ bptr, float* __restrict__ out,
    float* __restrict__ lossws)
{
    __shared__ __align__(16) short ylb[QB * K2];       // 16 KB bf16, XOR-swizzled
    __shared__ __align__(16) float scb[S_DIM * SCB_W]; // 18.4 KB z-transpose buffer
    __shared__ float cpart[16][33];
    __shared__ float cq[QB];
    __shared__ float asl[S_DIM];
    __shared__ float lred[8];

    const int tid = threadIdx.x;
    const int q0 = blockIdx.x * QB;
    const int wid = tid >> 6, l = tid & 63;
    const int lm = l & 15, lh = l >> 4;
    const int s_base = wid * 16;
    char* ylc = reinterpret_cast<char*>(ylb);

    // ---- stage y tile (32 rows x 230 f32) -> bf16 swizzled LDS ----
    const float4* ysrc4 = reinterpret_cast<const float4*>(y + (size_t)q0 * H_DIM);
    #pragma unroll
    for (int it = 0; it < 4; ++it) {
        int i4 = tid + 512 * it;
        if (i4 < (QB * H_DIM) / 4) {
            float4 v = ysrc4[i4];
            int e0 = i4 * 4;
            int r0 = e0 / H_DIM;               // const divide -> magic mul
            int c0 = e0 - r0 * H_DIM;          // even
            int e2 = e0 + 2;
            int r2 = e2 / H_DIM;
            int c2 = e2 - r2 * H_DIM;          // even
            int byt0 = ((r0 << 9) + (c0 << 1)) ^ ((r0 & 7) << 4);
            int byt2 = ((r2 << 9) + (c2 << 1)) ^ ((r2 & 7) << 4);
            *reinterpret_cast<unsigned*>(ylc + byt0) = packbf2(v.x, v.y);
            *reinterpret_cast<unsigned*>(ylc + byt2) = packbf2(v.z, v.w);
        }
    }
    if (tid < QB * (K2 - H_DIM) / 2) {   // zero-fill k=230..255: 32 rows x 13 pairs
        int r = tid & 31, c = H_DIM + 2 * (tid >> 5);
        int byt = ((r << 9) + (c << 1)) ^ ((r & 7) << 4);
        *reinterpret_cast<unsigned*>(ylc + byt) = 0u;
    }

    // ---- label prefetch (coalesced int4, store-phase indexing) ----
    // element i = tid + 512*it: s = i>>3, j = i&7 -> label[s*Q + q0 + 4j ..+3]
    int4 lab4[2];
    #pragma unroll
    for (int it = 0; it < 2; ++it) {
        int i = tid + 512 * it;
        int s = i >> 3, j = i & 7;
        lab4[it] = *reinterpret_cast<const int4*>(label + (size_t)s * Q_DIM + q0 + 4 * j);
    }

    // ---- A-frags + a[s] in registers (pre-barrier; overlaps y staging) ----
    short8 afr[8];
    {
        float ap = 0.f;
        const float* xrow = x + (size_t)(s_base + lm) * H_DIM;
        #pragma unroll
        for (int ks = 0; ks < 8; ++ks) {
            const int kof = ks * 32 + lh * 8;
            short8 a;
            #pragma unroll
            for (int j = 0; j < 4; ++j) {
                int k = kof + 2 * j;
                float2 x2 = {0.f, 0.f}, w2 = {0.f, 0.f};
                if (k < H_DIM) {
                    x2 = *reinterpret_cast<const float2*>(xrow + k);
                    w2 = *reinterpret_cast<const float2*>(w + k);
                }
                float p0 = w2.x * x2.x, p1 = w2.y * x2.y;
                a[2 * j]     = (short)bf16bits(p0);
                a[2 * j + 1] = (short)bf16bits(p1);
                ap = fmaf(p1, x2.y, fmaf(p0, x2.x, ap));   // w*x^2 (f32)
            }
            afr[ks] = a;
        }
        ap += __shfl_xor(ap, 16, 64);
        ap += __shfl_xor(ap, 32, 64);
        if (lh == 0) asl[s_base + lm] = ap;
    }

    __syncthreads();

    // ---- c[q] partials: r=tid&31 (q-row), ch=tid>>5 (16 k each) ----
    {
        const int r = tid & 31, ch = tid >> 5;     // ch in 0..15
        const int k0 = ch * 16;
        int byt0 = ((r << 9) + (k0 << 1)) ^ ((r & 7) << 4);
        int byt1 = ((r << 9) + ((k0 + 8) << 1)) ^ ((r & 7) << 4);
        short8 v8a = *reinterpret_cast<const short8*>(ylc + byt0);
        short8 v8b = *reinterpret_cast<const short8*>(ylc + byt1);
        float p = 0.f;
        #pragma unroll
        for (int j = 0; j < 8; ++j) {
            float va = bf16_to_f32(v8a[j]);
            float wa = (k0 + j < H_DIM) ? w[k0 + j] : 0.f;
            p = fmaf(wa * va, va, p);
        }
        #pragma unroll
        for (int j = 0; j < 8; ++j) {
            float vb = bf16_to_f32(v8b[j]);
            float wb = (k0 + 8 + j < H_DIM) ? w[k0 + 8 + j] : 0.f;
            p = fmaf(wb * vb, vb, p);
        }
        cpart[ch][r] = p;
    }
    __syncthreads();
    if (tid < QB) {
        float c = 0.f;
        #pragma unroll
        for (int ch = 0; ch < 16; ++ch) c += cpart[ch][tid];
        cq[tid] = c + bptr[0];                     // fold bias in
    }
    __syncthreads();

    // ---- MFMA k-loop: wave computes 16 s x 32 q (2 accs, A from registers) ----
    f32x4 acc0 = {0.f, 0.f, 0.f, 0.f};
    f32x4 acc1 = {0.f, 0.f, 0.f, 0.f};
    #pragma unroll
    for (int ks = 0; ks < K2 / 32; ++ks) {
        const int kof = ks * 32 + lh * 8;
        int byt0 = ((lm << 9) + (kof << 1)) ^ ((lm & 7) << 4);
        int byt1 = (((lm + 16) << 9) + (kof << 1)) ^ ((lm & 7) << 4);
        short8 bf0 = *reinterpret_cast<const short8*>(ylc + byt0);
        short8 bf1 = *reinterpret_cast<const short8*>(ylc + byt1);
        acc0 = __builtin_amdgcn_mfma_f32_16x16x32_bf16(afr[ks], bf0, acc0, 0, 0, 0);
        acc1 = __builtin_amdgcn_mfma_f32_16x16x32_bf16(afr[ks], bf1, acc1, 0, 0, 0);
    }

    // ---- z -> scb LDS (D row=(l>>4)*4+r (s), col=lm (q); 2-way banks = free) ----
    const float cq0 = cq[lm], cq1 = cq[lm + 16];
    #pragma unroll
    for (int r = 0; r < 4; ++r) {
        int s = s_base + lh * 4 + r;
        float az = asl[s];
        scb[s * SCB_W + lm]      = az + cq0 - 2.0f * acc0[r];
        scb[s * SCB_W + lm + 16] = az + cq1 - 2.0f * acc1[r];
    }
    __syncthreads();

    // ---- store phase: q-contiguous; sigmoid -> out (float4); BCE partial ----
    // bce = z*(1-lab) + log(1+exp(-z)), sharing exp(-z) with the sigmoid.
    float lsum = 0.f;
    #pragma unroll
    for (int it = 0; it < 2; ++it) {
        int i = tid + 512 * it;
        int s = i >> 3, j = i & 7;
        f32x4 z4 = *reinterpret_cast<const f32x4*>(&scb[s * SCB_W + 4 * j]);
        const int labv[4] = {lab4[it].x, lab4[it].y, lab4[it].z, lab4[it].w};
        f32x4 sc4;
        #pragma unroll
        for (int e = 0; e < 4; ++e) {
            float z = z4[e];
            float ez = __expf(-z);
            sc4[e] = 1.0f / (1.0f + ez);
            lsum += z * (1.0f - (float)labv[e]) + __logf(1.0f + ez);
        }
        *reinterpret_cast<f32x4*>(out + (size_t)s * Q_DIM + q0 + 4 * j) = sc4;
    }
    #pragma unroll
    for (int off = 32; off >= 1; off >>= 1) lsum += __shfl_down(lsum, off, 64);
    if (l == 0) lred[wid] = lsum;
    __syncthreads();
    if (tid == 0) {
        float blk = 0.f;
        #pragma unroll
        for (int i = 0; i < 8; ++i) blk += lred[i];
        lossws[blockIdx.x] = blk;
    }
}

// ---------------- Kernel 2: deterministic loss reduce ----------------
__global__ __launch_bounds__(256) void loss_reduce_kernel(
    const float* __restrict__ lossws, float* __restrict__ out)
{
    __shared__ float lred[4];
    const int tid = threadIdx.x;
    float p = lossws[tid];                         // NBLK=256 partials
    #pragma unroll
    for (int off = 32; off >= 1; off >>= 1) p += __shfl_down(p, off, 64);
    if ((tid & 63) == 0) lred[tid >> 6] = p;
    __syncthreads();
    if (tid == 0)
        out[SQ] = (lred[0] + lred[1] + lred[2] + lred[3]) * (1.0f / (float)SQ);
}

extern "C" void kernel_launch(void* const* d_in, const int* in_sizes, int n_in,
                              void* d_out, int out_size, void* d_ws, size_t ws_size,
                              hipStream_t stream) {
    const float* x = (const float*)d_in[0];     // [128,230]
    const float* y = (const float*)d_in[1];     // [8192,230]
    const int* label = (const int*)d_in[2];     // [128,8192]
    const float* w = (const float*)d_in[3];     // [230]
    const float* b = (const float*)d_in[4];     // [1]
    float* out = (float*)d_out;                 // [128*8192 + 1]

    float* lossws = (float*)d_ws;               // [256]

    main_kernel<<<NBLK, 512, 0, stream>>>(x, y, label, w, b, out, lossws);
    loss_reduce_kernel<<<1, 256, 0, stream>>>(lossws, out);
}

// Round 18
// 14.075 us; speedup vs baseline: 1.0954x; 1.0548x over previous
//
#include <hip/hip_runtime.h>
#include <hip/hip_bf16.h>

// S=128, Q=8192, H=230
//   logits[s,q] = a[s] + c[q] + b - 2*sum_k (w*x)[s,k]*y[q,k]
// r15 champion (14.7us) + three VALU cuts:
//   (1) sigmoid via v_rcp_f32 (kills 8 precise-divide sequences/thread)
//   (2) BCE log via product trick: sum log(1+e^-|z|) = ln2*log2(prod(...)),
//       one v_log per 8 elements instead of 8
//   (3) w staged to zero-padded f32 LDS -> guard-free c[q]
// Loss: per-block partial + tiny deterministic reduce kernel.

#define S_DIM 128
#define Q_DIM 8192
#define H_DIM 230
#define K2    256              // bf16 K padded to multiple of 32
#define SQ    (S_DIM * Q_DIM)
#define QB    32               // q-tile per block
#define NBLK  (Q_DIM / QB)     // 256 main blocks

using short8 = __attribute__((ext_vector_type(8))) short;   // 8 bf16 (4 VGPRs)
using f32x4  = __attribute__((ext_vector_type(4))) float;

__device__ __forceinline__ float bf16_to_f32(short bits) {
    unsigned u = ((unsigned)(unsigned short)bits) << 16;
    return __uint_as_float(u);
}
__device__ __forceinline__ unsigned short bf16bits(float f) {
    __hip_bfloat16 h = __float2bfloat16(f);
    return *reinterpret_cast<unsigned short*>(&h);
}
__device__ __forceinline__ unsigned packbf2(float lo, float hi) {
    return (unsigned)bf16bits(lo) | ((unsigned)bf16bits(hi) << 16);
}

// ---------------- Kernel 1: main (MFMA GEMM + sigmoid + BCE) ----------------
// grid=256, block=512 (8 waves). Block: all 128 s x 32 q.
// Wave wid: s in [16*wid, 16*wid+16), q-halves [q0,q0+16) and [q0+16,q0+32).
__global__ __launch_bounds__(512, 2) void main_kernel(
    const float* __restrict__ x, const float* __restrict__ y,
    const int* __restrict__ label, const float* __restrict__ w,
    const float* __restrict__ bptr, float* __restrict__ out,
    float* __restrict__ lossws)
{
    __shared__ __align__(16) short ylb[QB * K2];   // 16 KB bf16, XOR-swizzled
    __shared__ float wl[K2];                       // w zero-padded, f32
    __shared__ float cpart[16][33];
    __shared__ float cq[QB];
    __shared__ float asl[S_DIM];
    __shared__ float lred[8];

    const int tid = threadIdx.x;
    const int q0 = blockIdx.x * QB;
    const int wid = tid >> 6, l = tid & 63;
    const int lm = l & 15, lh = l >> 4;
    const int s_base = wid * 16;
    char* ylc = reinterpret_cast<char*>(ylb);

    // ---- w -> LDS (zero-padded; consumed post-barrier in c[q]) ----
    if (tid < K2) wl[tid] = (tid < H_DIM) ? w[tid] : 0.0f;

    // ---- stage y tile (32 rows x 230 f32) -> bf16 swizzled LDS ----
    // One contiguous span of 32*230 = 7360 f32 = 1840 float4, 16B-aligned.
    // Each float4 splits into two row-contained even-column bf16 pairs ->
    // two packed ds_write_b32 (swizzle XOR touches bits>=4 only).
    const float4* ysrc4 = reinterpret_cast<const float4*>(y + (size_t)q0 * H_DIM);
    #pragma unroll
    for (int it = 0; it < 4; ++it) {
        int i4 = tid + 512 * it;
        if (i4 < (QB * H_DIM) / 4) {
            float4 v = ysrc4[i4];
            int e0 = i4 * 4;
            int r0 = e0 / H_DIM;               // const divide -> magic mul
            int c0 = e0 - r0 * H_DIM;          // even
            int e2 = e0 + 2;
            int r2 = e2 / H_DIM;
            int c2 = e2 - r2 * H_DIM;          // even
            int byt0 = ((r0 << 9) + (c0 << 1)) ^ ((r0 & 7) << 4);
            int byt2 = ((r2 << 9) + (c2 << 1)) ^ ((r2 & 7) << 4);
            *reinterpret_cast<unsigned*>(ylc + byt0) = packbf2(v.x, v.y);
            *reinterpret_cast<unsigned*>(ylc + byt2) = packbf2(v.z, v.w);
        }
    }
    if (tid < QB * (K2 - H_DIM) / 2) {   // zero-fill k=230..255: 32 rows x 13 pairs
        int r = tid & 31, c = H_DIM + 2 * (tid >> 5);
        int byt = ((r << 9) + (c << 1)) ^ ((r & 7) << 4);
        *reinterpret_cast<unsigned*>(ylc + byt) = 0u;
    }

    // ---- label prefetch: issue AFTER staging reads, consume in epilogue ----
    int labs[2][4];
    {
        const size_t ob = (size_t)(s_base + lh * 4) * Q_DIM + q0 + lm;
        #pragma unroll
        for (int r = 0; r < 4; ++r) {
            labs[0][r] = label[ob + (size_t)r * Q_DIM];
            labs[1][r] = label[ob + (size_t)r * Q_DIM + 16];
        }
    }

    // ---- A-frags + a[s] in registers (pre-barrier; overlaps y staging) ----
    // Lane's A row = s_base+lm; k = ks*32 + lh*8 + e. float2 pairs (8B-aligned
    // always: rows start at even f32 offsets, k even; pair valid iff k<230).
    // w loads are uniform across the 16 lm-lanes -> L1 broadcast.
    short8 afr[8];
    {
        float ap = 0.f;
        const float* xrow = x + (size_t)(s_base + lm) * H_DIM;
        #pragma unroll
        for (int ks = 0; ks < 8; ++ks) {
            const int kof = ks * 32 + lh * 8;
            short8 a;
            #pragma unroll
            for (int j = 0; j < 4; ++j) {
                int k = kof + 2 * j;
                float2 x2 = {0.f, 0.f}, w2 = {0.f, 0.f};
                if (k < H_DIM) {
                    x2 = *reinterpret_cast<const float2*>(xrow + k);
                    w2 = *reinterpret_cast<const float2*>(w + k);
                }
                float p0 = w2.x * x2.x, p1 = w2.y * x2.y;
                a[2 * j]     = (short)bf16bits(p0);
                a[2 * j + 1] = (short)bf16bits(p1);
                ap = fmaf(p1, x2.y, fmaf(p0, x2.x, ap));   // w*x^2 (f32)
            }
            afr[ks] = a;
        }
        ap += __shfl_xor(ap, 16, 64);
        ap += __shfl_xor(ap, 32, 64);
        if (lh == 0) asl[s_base + lm] = ap;
    }

    __syncthreads();

    // ---- c[q] partials: r=tid&31 (q-row), ch=tid>>5 (16 k each) ----
    {
        const int r = tid & 31, ch = tid >> 5;     // ch in 0..15
        const int k0 = ch * 16;
        int byt0 = ((r << 9) + (k0 << 1)) ^ ((r & 7) << 4);
        int byt1 = ((r << 9) + ((k0 + 8) << 1)) ^ ((r & 7) << 4);
        short8 v8a = *reinterpret_cast<const short8*>(ylc + byt0);
        short8 v8b = *reinterpret_cast<const short8*>(ylc + byt1);
        float p = 0.f;
        #pragma unroll
        for (int j = 0; j < 8; ++j) {
            float va = bf16_to_f32(v8a[j]);
            p = fmaf(wl[k0 + j] * va, va, p);
        }
        #pragma unroll
        for (int j = 0; j < 8; ++j) {
            float vb = bf16_to_f32(v8b[j]);
            p = fmaf(wl[k0 + 8 + j] * vb, vb, p);
        }
        cpart[ch][r] = p;
    }
    __syncthreads();
    if (tid < QB) {
        float c = 0.f;
        #pragma unroll
        for (int ch = 0; ch < 16; ++ch) c += cpart[ch][tid];
        cq[tid] = c + bptr[0];                     // fold bias in
    }
    __syncthreads();

    // ---- MFMA k-loop: wave computes 16 s x 32 q (2 accs, A from registers) ----
    f32x4 acc0 = {0.f, 0.f, 0.f, 0.f};
    f32x4 acc1 = {0.f, 0.f, 0.f, 0.f};
    #pragma unroll
    for (int ks = 0; ks < K2 / 32; ++ks) {
        const int kof = ks * 32 + lh * 8;
        int byt0 = ((lm << 9) + (kof << 1)) ^ ((lm & 7) << 4);
        int byt1 = (((lm + 16) << 9) + (kof << 1)) ^ ((lm & 7) << 4);
        short8 bf0 = *reinterpret_cast<const short8*>(ylc + byt0);
        short8 bf1 = *reinterpret_cast<const short8*>(ylc + byt1);
        acc0 = __builtin_amdgcn_mfma_f32_16x16x32_bf16(afr[ks], bf0, acc0, 0, 0, 0);
        acc1 = __builtin_amdgcn_mfma_f32_16x16x32_bf16(afr[ks], bf1, acc1, 0, 0, 0);
    }

    // ---- epilogue ----
    // z = a[s]+c[q]+b-2*dot; sc = rcp(1+e^-z) (v_rcp, 1-ulp);
    // bce = z*(1-lab) + max(-z,0) + log(1+e^-|z|); the log terms are
    // accumulated as a product P = prod(1+e^-|z|) in (1,256] and folded
    // with ONE v_log: lsum += ln2 * log2(P).
    float asum_l = 0.f, prod = 1.f;
    const float cq0 = cq[lm], cq1 = cq[lm + 16];
    #pragma unroll
    for (int r = 0; r < 4; ++r) {
        int s = s_base + lh * 4 + r;               // D row=(l>>4)*4+r, col=l&15
        size_t o = (size_t)s * Q_DIM + q0 + lm;
        float az = asl[s];
        {
            float z = az + cq0 - 2.0f * acc0[r];
            float ez = __expf(-z);
            out[o] = __builtin_amdgcn_rcpf(1.0f + ez);
            float lab = (float)labs[0][r];
            asum_l += z * (1.0f - lab) + fmaxf(-z, 0.0f);
            float em = (z >= 0.0f) ? ez : __builtin_amdgcn_rcpf(ez);
            prod *= (1.0f + em);
        }
        {
            float z = az + cq1 - 2.0f * acc1[r];
            float ez = __expf(-z);
            out[o + 16] = __builtin_amdgcn_rcpf(1.0f + ez);
            float lab = (float)labs[1][r];
            asum_l += z * (1.0f - lab) + fmaxf(-z, 0.0f);
            float em = (z >= 0.0f) ? ez : __builtin_amdgcn_rcpf(ez);
            prod *= (1.0f + em);
        }
    }
    float lsum = asum_l + 0.69314718055994531f * __log2f(prod);
    #pragma unroll
    for (int off = 32; off >= 1; off >>= 1) lsum += __shfl_down(lsum, off, 64);
    if (l == 0) lred[wid] = lsum;
    __syncthreads();
    if (tid == 0) {
        float blk = 0.f;
        #pragma unroll
        for (int i = 0; i < 8; ++i) blk += lred[i];
        lossws[blockIdx.x] = blk;
    }
}

// ---------------- Kernel 2: deterministic loss reduce ----------------
__global__ __launch_bounds__(256) void loss_reduce_kernel(
    const float* __restrict__ lossws, float* __restrict__ out)
{
    __shared__ float lred[4];
    const int tid = threadIdx.x;
    float p = lossws[tid];                         // NBLK=256 partials
    #pragma unroll
    for (int off = 32; off >= 1; off >>= 1) p += __shfl_down(p, off, 64);
    if ((tid & 63) == 0) lred[tid >> 6] = p;
    __syncthreads();
    if (tid == 0)
        out[SQ] = (lred[0] + lred[1] + lred[2] + lred[3]) * (1.0f / (float)SQ);
}

extern "C" void kernel_launch(void* const* d_in, const int* in_sizes, int n_in,
                              void* d_out, int out_size, void* d_ws, size_t ws_size,
                              hipStream_t stream) {
    const float* x = (const float*)d_in[0];     // [128,230]
    const float* y = (const float*)d_in[1];     // [8192,230]
    const int* label = (const int*)d_in[2];     // [128,8192]
    const float* w = (const float*)d_in[3];     // [230]
    const float* b = (const float*)d_in[4];     // [1]
    float* out = (float*)d_out;                 // [128*8192 + 1]

    float* lossws = (float*)d_ws;               // [256]

    main_kernel<<<NBLK, 512, 0, stream>>>(x, y, label, w, b, out, lossws);
    loss_reduce_kernel<<<1, 256, 0, stream>>>(lossws, out);
}

// Round 19
// 13.750 us; speedup vs baseline: 1.1212x; 1.0236x over previous
//
#include <hip/hip_runtime.h>
#include <hip/hip_bf16.h>

// S=128, Q=8192, H=230
//   logits[s,q] = a[s] + c[q] + b - 2*sum_k (w*x)[s,k]*y[q,k]
// r18 champion (14.07us) + two VALU-pocket cuts:
//   (1) A-build unguarded for ks=0..6 (kof+7 <= 229 always); ks=7 boundary
//       special-cased (lh==0: 3 valid pairs; lh>=1: zero) - bitwise identical
//   (2) branch-free single-exp epilogue: em=exp(-|z|), t=rcp(1+em),
//       sc = z>=0 ? t : em*t, prod *= (1+em) -> 2 transcendentals/element
// Loss: per-block partial + tiny deterministic reduce kernel.

#define S_DIM 128
#define Q_DIM 8192
#define H_DIM 230
#define K2    256              // bf16 K padded to multiple of 32
#define SQ    (S_DIM * Q_DIM)
#define QB    32               // q-tile per block
#define NBLK  (Q_DIM / QB)     // 256 main blocks

using short8 = __attribute__((ext_vector_type(8))) short;   // 8 bf16 (4 VGPRs)
using f32x4  = __attribute__((ext_vector_type(4))) float;

__device__ __forceinline__ float bf16_to_f32(short bits) {
    unsigned u = ((unsigned)(unsigned short)bits) << 16;
    return __uint_as_float(u);
}
__device__ __forceinline__ unsigned short bf16bits(float f) {
    __hip_bfloat16 h = __float2bfloat16(f);
    return *reinterpret_cast<unsigned short*>(&h);
}
__device__ __forceinline__ unsigned packbf2(float lo, float hi) {
    return (unsigned)bf16bits(lo) | ((unsigned)bf16bits(hi) << 16);
}

// ---------------- Kernel 1: main (MFMA GEMM + sigmoid + BCE) ----------------
// grid=256, block=512 (8 waves). Block: all 128 s x 32 q.
// Wave wid: s in [16*wid, 16*wid+16), q-halves [q0,q0+16) and [q0+16,q0+32).
__global__ __launch_bounds__(512, 2) void main_kernel(
    const float* __restrict__ x, const float* __restrict__ y,
    const int* __restrict__ label, const float* __restrict__ w,
    const float* __restrict__ bptr, float* __restrict__ out,
    float* __restrict__ lossws)
{
    __shared__ __align__(16) short ylb[QB * K2];   // 16 KB bf16, XOR-swizzled
    __shared__ float wl[K2];                       // w zero-padded, f32
    __shared__ float cpart[16][33];
    __shared__ float cq[QB];
    __shared__ float asl[S_DIM];
    __shared__ float lred[8];

    const int tid = threadIdx.x;
    const int q0 = blockIdx.x * QB;
    const int wid = tid >> 6, l = tid & 63;
    const int lm = l & 15, lh = l >> 4;
    const int s_base = wid * 16;
    char* ylc = reinterpret_cast<char*>(ylb);

    // ---- w -> LDS (zero-padded; consumed post-barrier in c[q]) ----
    if (tid < K2) wl[tid] = (tid < H_DIM) ? w[tid] : 0.0f;

    // ---- stage y tile (32 rows x 230 f32) -> bf16 swizzled LDS ----
    const float4* ysrc4 = reinterpret_cast<const float4*>(y + (size_t)q0 * H_DIM);
    #pragma unroll
    for (int it = 0; it < 4; ++it) {
        int i4 = tid + 512 * it;
        if (i4 < (QB * H_DIM) / 4) {
            float4 v = ysrc4[i4];
            int e0 = i4 * 4;
            int r0 = e0 / H_DIM;               // const divide -> magic mul
            int c0 = e0 - r0 * H_DIM;          // even
            int e2 = e0 + 2;
            int r2 = e2 / H_DIM;
            int c2 = e2 - r2 * H_DIM;          // even
            int byt0 = ((r0 << 9) + (c0 << 1)) ^ ((r0 & 7) << 4);
            int byt2 = ((r2 << 9) + (c2 << 1)) ^ ((r2 & 7) << 4);
            *reinterpret_cast<unsigned*>(ylc + byt0) = packbf2(v.x, v.y);
            *reinterpret_cast<unsigned*>(ylc + byt2) = packbf2(v.z, v.w);
        }
    }
    if (tid < QB * (K2 - H_DIM) / 2) {   // zero-fill k=230..255: 32 rows x 13 pairs
        int r = tid & 31, c = H_DIM + 2 * (tid >> 5);
        int byt = ((r << 9) + (c << 1)) ^ ((r & 7) << 4);
        *reinterpret_cast<unsigned*>(ylc + byt) = 0u;
    }

    // ---- label prefetch: issue AFTER staging reads, consume in epilogue ----
    int labs[2][4];
    {
        const size_t ob = (size_t)(s_base + lh * 4) * Q_DIM + q0 + lm;
        #pragma unroll
        for (int r = 0; r < 4; ++r) {
            labs[0][r] = label[ob + (size_t)r * Q_DIM];
            labs[1][r] = label[ob + (size_t)r * Q_DIM + 16];
        }
    }

    // ---- A-frags + a[s] in registers (pre-barrier; overlaps y staging) ----
    // Lane's A row = s_base+lm; k = ks*32 + lh*8 + 2j. For ks<=6:
    // k <= 6*32+3*8+6 = 222 < 230 -> UNGUARDED float2 loads (8B-aligned:
    // rows start at even f32 offsets, k even). ks=7: lh==0 has pairs at
    // 224/226/228 valid + 230 zero; lh>=1 all zero.
    short8 afr[8];
    {
        float ap = 0.f;
        const float* xrow = x + (size_t)(s_base + lm) * H_DIM;
        #pragma unroll
        for (int ks = 0; ks < 7; ++ks) {
            const int kof = ks * 32 + lh * 8;
            short8 a;
            #pragma unroll
            for (int j = 0; j < 4; ++j) {
                int k = kof + 2 * j;
                float2 x2 = *reinterpret_cast<const float2*>(xrow + k);
                float2 w2 = *reinterpret_cast<const float2*>(w + k);
                float p0 = w2.x * x2.x, p1 = w2.y * x2.y;
                a[2 * j]     = (short)bf16bits(p0);
                a[2 * j + 1] = (short)bf16bits(p1);
                ap = fmaf(p1, x2.y, fmaf(p0, x2.x, ap));   // w*x^2 (f32)
            }
            afr[ks] = a;
        }
        {   // ks = 7 boundary tile
            short8 a = {0, 0, 0, 0, 0, 0, 0, 0};
            if (lh == 0) {
                #pragma unroll
                for (int j = 0; j < 3; ++j) {
                    int k = 224 + 2 * j;
                    float2 x2 = *reinterpret_cast<const float2*>(xrow + k);
                    float2 w2 = *reinterpret_cast<const float2*>(w + k);
                    float p0 = w2.x * x2.x, p1 = w2.y * x2.y;
                    a[2 * j]     = (short)bf16bits(p0);
                    a[2 * j + 1] = (short)bf16bits(p1);
                    ap = fmaf(p1, x2.y, fmaf(p0, x2.x, ap));
                }
            }
            afr[7] = a;
        }
        ap += __shfl_xor(ap, 16, 64);
        ap += __shfl_xor(ap, 32, 64);
        if (lh == 0) asl[s_base + lm] = ap;
    }

    __syncthreads();

    // ---- c[q] partials: r=tid&31 (q-row), ch=tid>>5 (16 k each) ----
    {
        const int r = tid & 31, ch = tid >> 5;     // ch in 0..15
        const int k0 = ch * 16;
        int byt0 = ((r << 9) + (k0 << 1)) ^ ((r & 7) << 4);
        int byt1 = ((r << 9) + ((k0 + 8) << 1)) ^ ((r & 7) << 4);
        short8 v8a = *reinterpret_cast<const short8*>(ylc + byt0);
        short8 v8b = *reinterpret_cast<const short8*>(ylc + byt1);
        float p = 0.f;
        #pragma unroll
        for (int j = 0; j < 8; ++j) {
            float va = bf16_to_f32(v8a[j]);
            p = fmaf(wl[k0 + j] * va, va, p);
        }
        #pragma unroll
        for (int j = 0; j < 8; ++j) {
            float vb = bf16_to_f32(v8b[j]);
            p = fmaf(wl[k0 + 8 + j] * vb, vb, p);
        }
        cpart[ch][r] = p;
    }
    __syncthreads();
    if (tid < QB) {
        float c = 0.f;
        #pragma unroll
        for (int ch = 0; ch < 16; ++ch) c += cpart[ch][tid];
        cq[tid] = c + bptr[0];                     // fold bias in
    }
    __syncthreads();

    // ---- MFMA k-loop: wave computes 16 s x 32 q (2 accs, A from registers) ----
    f32x4 acc0 = {0.f, 0.f, 0.f, 0.f};
    f32x4 acc1 = {0.f, 0.f, 0.f, 0.f};
    #pragma unroll
    for (int ks = 0; ks < K2 / 32; ++ks) {
        const int kof = ks * 32 + lh * 8;
        int byt0 = ((lm << 9) + (kof << 1)) ^ ((lm & 7) << 4);
        int byt1 = (((lm + 16) << 9) + (kof << 1)) ^ ((lm & 7) << 4);
        short8 bf0 = *reinterpret_cast<const short8*>(ylc + byt0);
        short8 bf1 = *reinterpret_cast<const short8*>(ylc + byt1);
        acc0 = __builtin_amdgcn_mfma_f32_16x16x32_bf16(afr[ks], bf0, acc0, 0, 0, 0);
        acc1 = __builtin_amdgcn_mfma_f32_16x16x32_bf16(afr[ks], bf1, acc1, 0, 0, 0);
    }

    // ---- epilogue (branch-free, 2 transcendentals/element) ----
    // em = e^-|z| in (0,1]; t = rcp(1+em); sigmoid = z>=0 ? t : em*t.
    // bce = z*(1-lab) + max(-z,0) + log(1+e^-|z|), log terms folded as
    // ONE v_log per thread: lsum += ln2 * log2(prod(1+em)), prod <= 256.
    float asum_l = 0.f, prod = 1.f;
    const float cq0 = cq[lm], cq1 = cq[lm + 16];
    #pragma unroll
    for (int r = 0; r < 4; ++r) {
        int s = s_base + lh * 4 + r;               // D row=(l>>4)*4+r, col=l&15
        size_t o = (size_t)s * Q_DIM + q0 + lm;
        float az = asl[s];
        {
            float z = az + cq0 - 2.0f * acc0[r];
            float em = __expf(-fabsf(z));
            float opem = 1.0f + em;
            float t = __builtin_amdgcn_rcpf(opem);
            out[o] = (z >= 0.0f) ? t : em * t;
            float lab = (float)labs[0][r];
            asum_l += z * (1.0f - lab) + fmaxf(-z, 0.0f);
            prod *= opem;
        }
        {
            float z = az + cq1 - 2.0f * acc1[r];
            float em = __expf(-fabsf(z));
            float opem = 1.0f + em;
            float t = __builtin_amdgcn_rcpf(opem);
            out[o + 16] = (z >= 0.0f) ? t : em * t;
            float lab = (float)labs[1][r];
            asum_l += z * (1.0f - lab) + fmaxf(-z, 0.0f);
            prod *= opem;
        }
    }
    float lsum = asum_l + 0.69314718055994531f * __log2f(prod);
    #pragma unroll
    for (int off = 32; off >= 1; off >>= 1) lsum += __shfl_down(lsum, off, 64);
    if (l == 0) lred[wid] = lsum;
    __syncthreads();
    if (tid == 0) {
        float blk = 0.f;
        #pragma unroll
        for (int i = 0; i < 8; ++i) blk += lred[i];
        lossws[blockIdx.x] = blk;
    }
}

// ---------------- Kernel 2: deterministic loss reduce ----------------
__global__ __launch_bounds__(256) void loss_reduce_kernel(
    const float* __restrict__ lossws, float* __restrict__ out)
{
    __shared__ float lred[4];
    const int tid = threadIdx.x;
    float p = lossws[tid];                         // NBLK=256 partials
    #pragma unroll
    for (int off = 32; off >= 1; off >>= 1) p += __shfl_down(p, off, 64);
    if ((tid & 63) == 0) lred[tid >> 6] = p;
    __syncthreads();
    if (tid == 0)
        out[SQ] = (lred[0] + lred[1] + lred[2] + lred[3]) * (1.0f / (float)SQ);
}

extern "C" void kernel_launch(void* const* d_in, const int* in_sizes, int n_in,
                              void* d_out, int out_size, void* d_ws, size_t ws_size,
                              hipStream_t stream) {
    const float* x = (const float*)d_in[0];     // [128,230]
    const float* y = (const float*)d_in[1];     // [8192,230]
    const int* label = (const int*)d_in[2];     // [128,8192]
    const float* w = (const float*)d_in[3];     // [230]
    const float* b = (const float*)d_in[4];     // [1]
    float* out = (float*)d_out;                 // [128*8192 + 1]

    float* lossws = (float*)d_ws;               // [256]

    main_kernel<<<NBLK, 512, 0, stream>>>(x, y, label, w, b, out, lossws);
    loss_reduce_kernel<<<1, 256, 0, stream>>>(lossws, out);
}